// Round 3
// baseline (367.600 us; speedup 1.0000x reference)
//
#include <hip/hip_runtime.h>
#include <cstdint>

#define EPSF 1e-5f

// ============================== prep ==============================
// w2bits: [co][tap] bit=ci.  wfcb: POS-MAJOR [pos][j] bit=c (feature k = c*36+pos).
// wlt: [k][j] (j padded to 576).  BN3 constants padded with 0.
__global__ __launch_bounds__(256) void prep_kernel(
    const float* __restrict__ w2, const float* __restrict__ wfc,
    const float* __restrict__ g3, const float* __restrict__ be3,
    const float* __restrict__ m3, const float* __restrict__ v3,
    const float* __restrict__ wlast,
    uint32_t* __restrict__ w2bits, uint32_t* __restrict__ wfcb,
    float* __restrict__ inv3p, float* __restrict__ sh3p, float* __restrict__ wlt)
{
    int id = blockIdx.x * 256 + threadIdx.x;
    if (id < 288) {                       // w2 sign pack: [co][ky*3+kx], bit ci
        int co = id / 9, r = id % 9;
        uint32_t b = 0;
        for (int ci = 0; ci < 32; ci++)
            b |= (uint32_t)(w2[(co * 32 + ci) * 9 + r] < 0.f) << ci;
        w2bits[id] = b;
        return;
    }
    id -= 288;
    if (id < 36 * 576) {                  // w_fc pack: [pos][j], bit c
        int pos = id / 576, j = id % 576;
        uint32_t b = 0;
        if (j < 516) {
            const float* row = wfc + j * 1152 + pos;
            for (int c = 0; c < 32; c++)
                b |= (uint32_t)(row[c * 36] < 0.f) << c;
        }
        wfcb[id] = b;
        return;
    }
    id -= 36 * 576;
    if (id < 576) {                       // BN3 constants (pad -> 0)
        float iv = 0.f, sh = 0.f;
        if (id < 516) {
            iv = g3[id] / sqrtf(__fadd_rn(v3[id], EPSF));
            sh = __fsub_rn(be3[id], __fmul_rn(m3[id], iv));
        }
        inv3p[id] = iv; sh3p[id] = sh;
        return;
    }
    id -= 576;
    if (id < 5760) {                      // w_last transpose: wlt[k*576 + j]
        int k = id / 576, j = id % 576;
        wlt[id] = (j < 516) ? wlast[k * 516 + j] : 0.f;
    }
}

// ================== conv1 fp64 sign recheck (rare) ==================
__device__ __noinline__ bool recheck_sign(const float* xim, const float* wl,
                                          int y, int p, int co,
                                          float b0c, float ivc, float shc)
{
    double ad = 0.0;
    for (int ci = 0; ci < 8; ci++)
        for (int ky = 0; ky < 3; ky++)
            for (int kx = 0; kx < 3; kx++)
                ad = fma((double)xim[ci * 256 + (y + ky) * 16 + p + kx],
                         (double)wl[(((ci * 3 + ky) * 3) + kx) * 32 + co], ad);
    double yd = (ad + (double)b0c) * (double)ivc + (double)shc;
    return yd < 0.0;
}

// ============================== convA ==============================
// conv1 + bias + BN1 + sign -> bitpack over 32 channels.
// thread = (row rg = img*14+y, channel pair cg). 28 accumulators — must fit
// arch VGPRs (the 56-acc version hid half in AGPRs: v_accvgpr ping-pong ~2x
// VALU inflation + unified-file occupancy cap at 4 waves/SIMD).
// Per-accumulator fp32 op order (ci,ky,kx) identical to the passing version.
__global__ __launch_bounds__(256, 4) void convA(
    const float* __restrict__ x, const float* __restrict__ w0,
    const float* __restrict__ b0, const float* __restrict__ g1,
    const float* __restrict__ be1, const float* __restrict__ m1,
    const float* __restrict__ v1, uint32_t* __restrict__ s1bits)
{
    __shared__ float wl[2304];            // [ci][ky][kx][co]
    __shared__ float bb[32], iv[32], sh[32];
    __shared__ uint32_t pack[16][14];     // 16 rows per block

    const int t = threadIdx.x;
    for (int i = t; i < 2304; i += 256) {
        int co = i & 31, q = i >> 5;
        int kx = q % 3, ky = (q / 3) % 3, ci = q / 9;
        wl[i] = w0[co * 72 + ci * 9 + ky * 3 + kx];
    }
    if (t < 32) {
        float ivv = g1[t] / sqrtf(__fadd_rn(v1[t], EPSF));
        iv[t] = ivv;
        sh[t] = __fsub_rn(be1[t], __fmul_rn(m1[t], ivv));
        bb[t] = b0[t];
    }
    for (int i = t; i < 224; i += 256) ((uint32_t*)pack)[i] = 0u;
    __syncthreads();

    const int tg  = blockIdx.x * 256 + t;
    const int rg  = tg >> 4;              // global row = img*14 + y
    const int cg  = tg & 15;              // channel pair (co = 2cg, 2cg+1)
    const int img = rg / 14;
    const int y   = rg - img * 14;
    const float* xim = x + img * 2048;

    float acc[2][14];
    #pragma unroll
    for (int c = 0; c < 2; c++)
        #pragma unroll
        for (int p = 0; p < 14; p++) acc[c][p] = 0.f;

    for (int ci = 0; ci < 8; ci++) {
        const float* base = xim + ci * 256 + y * 16;
        #pragma unroll
        for (int ky = 0; ky < 3; ky++) {
            const float4* rp = (const float4*)(base + ky * 16);
            float4 r0 = rp[0], r1 = rp[1], r2 = rp[2], r3 = rp[3];
            float px[16] = { r0.x, r0.y, r0.z, r0.w, r1.x, r1.y, r1.z, r1.w,
                             r2.x, r2.y, r2.z, r2.w, r3.x, r3.y, r3.z, r3.w };
            #pragma unroll
            for (int kx = 0; kx < 3; kx++) {
                float2 wv = *(const float2*)&wl[(((ci * 3 + ky) * 3) + kx) * 32 + 2 * cg];
                #pragma unroll
                for (int p = 0; p < 14; p++) {
                    acc[0][p] = fmaf(px[p + kx], wv.x, acc[0][p]);
                    acc[1][p] = fmaf(px[p + kx], wv.y, acc[1][p]);
                }
            }
        }
    }

    float b0c[2], ivc[2], shc[2];
    #pragma unroll
    for (int c = 0; c < 2; c++) {
        b0c[c] = bb[2 * cg + c]; ivc[c] = iv[2 * cg + c]; shc[c] = sh[2 * cg + c];
    }

    const int rloc = t >> 4;
    const uint32_t shift = (uint32_t)(cg * 2);
    uint32_t prov = 0u, need = 0u;        // bit idx = p*2 + c

    #pragma unroll
    for (int p = 0; p < 14; p++) {
        uint32_t nib = 0;
        #pragma unroll
        for (int c = 0; c < 2; c++) {
            float h  = __fadd_rn(acc[c][p], b0c[c]);
            float yv = __fadd_rn(__fmul_rn(h, ivc[c]), shc[c]);
            bool bit = (yv < 0.f);
            int idx = p * 2 + c;
            prov |= (uint32_t)bit << idx;
            if (fabsf(yv) < 3e-4f) need |= 1u << idx;
            nib |= (uint32_t)bit << c;
        }
        atomicOr(&pack[rloc][p], nib << shift);
    }
    // rare fp64 recheck of borderline signs; fix bits with atomicXor
    while (need) {
        int idx = __ffs(need) - 1;
        need &= need - 1u;
        int p = idx >> 1, c = idx & 1;
        bool nb = recheck_sign(xim, wl, y, p, 2 * cg + c, b0c[c], ivc[c], shc[c]);
        if (nb != (bool)((prov >> idx) & 1u))
            atomicXor(&pack[rloc][p], 1u << (shift + c));
    }
    __syncthreads();

    for (int i = t; i < 224; i += 256) {
        int rgo = blockIdx.x * 16 + (i / 14);
        int p   = i % 14;
        s1bits[rgo * 14 + p] = ((const uint32_t*)pack)[i];
    }
}

// ============================== convB ==============================
// binary conv2 + BN2 + hardtanh + maxpool + sign.
// One image per wave. lane = c + 32*h: channel c, y-half h. Weights in 9 regs,
// sliding 4x4 window regs with broadcast b64 LDS refills (the old layout issued
// ~810 scalar ds_reads/thread — LDS-issue-bound ~60us).
// Output POS-MAJOR: fcin[img*36 + pos], bit c — one __ballot yields two words.
__global__ __launch_bounds__(256) void convB(
    const uint32_t* __restrict__ s1bits, const uint32_t* __restrict__ w2bits,
    const float* __restrict__ g2, const float* __restrict__ be2,
    const float* __restrict__ m2, const float* __restrict__ v2,
    uint32_t* __restrict__ fcin)
{
    __shared__ uint32_t s1l[4][196];
    const int t = threadIdx.x, wid = t >> 6, lane = t & 63;
    const int img = blockIdx.x * 4 + wid;

    for (int i = lane; i < 196; i += 64) s1l[wid][i] = s1bits[img * 196 + i];

    const int c = lane & 31, h = lane >> 5;
    uint32_t wr[9];
    #pragma unroll
    for (int k = 0; k < 9; k++) wr[k] = w2bits[c * 9 + k];
    float ivv = g2[c] / sqrtf(__fadd_rn(v2[c], EPSF));
    float shv = __fsub_rn(be2[c], __fmul_rn(m2[c], ivv));
    __syncthreads();

    const uint32_t* s1w = s1l[wid];
    uint32_t* outp = fcin + img * 36;

    for (int yy = 0; yy < 3; yy++) {
        const int y2 = yy + 3 * h;
        const int rbase = 2 * y2 * 14;
        uint32_t win[4][4];
        #pragma unroll
        for (int rr = 0; rr < 4; rr++) {
            uint2 a = *(const uint2*)&s1w[rbase + rr * 14];
            uint2 b = *(const uint2*)&s1w[rbase + rr * 14 + 2];
            win[rr][0] = a.x; win[rr][1] = a.y; win[rr][2] = b.x; win[rr][3] = b.y;
        }
        for (int x2 = 0; x2 < 6; x2++) {
            if (x2 > 0) {
                #pragma unroll
                for (int rr = 0; rr < 4; rr++) {
                    win[rr][0] = win[rr][2]; win[rr][1] = win[rr][3];
                    uint2 b = *(const uint2*)&s1w[rbase + rr * 14 + 2 * x2 + 2];
                    win[rr][2] = b.x; win[rr][3] = b.y;
                }
            }
            int mx = -10000;
            #pragma unroll
            for (int dy = 0; dy < 2; dy++)
                #pragma unroll
                for (int dx = 0; dx < 2; dx++) {
                    int p = 0;
                    #pragma unroll
                    for (int ky = 0; ky < 3; ky++)
                        #pragma unroll
                        for (int kx = 0; kx < 3; kx++)
                            p += __popc(win[dy + ky][dx + kx] ^ wr[ky * 3 + kx]);
                    mx = max(mx, 288 - 2 * p);
                }
            float yv = __fadd_rn(__fmul_rn((float)mx, ivv), shv);
            unsigned long long mb = __ballot(yv < 0.f);
            int pos = y2 * 6 + x2;        // each lane's own pos (halves differ)
            if (lane == 0)  outp[pos] = (uint32_t)mb;
            if (lane == 32) outp[pos] = (uint32_t)(mb >> 32);
        }
    }
}

// ============================== fcC ==============================
// binary FC + BN3 + hardtanh + final 516x10 linear.
// wave = 2 batches; lane covers j = lane + 64q. w-loop OUTER with 18 popcount
// accumulators in regs -> 72 ds_reads total (was 1296/wave, ~25us LDS-bound).
// wfcb is pos-major, matching convB's fcin words.
__global__ __launch_bounds__(256) void fcC(
    const uint32_t* __restrict__ fcin, const uint32_t* __restrict__ wfcb,
    const float* __restrict__ inv3p, const float* __restrict__ sh3p,
    const float* __restrict__ wlt, const float* __restrict__ blast,
    float* __restrict__ out)
{
    __shared__ uint32_t l_in[288];        // 8 batches x 36 words
    const int t = threadIdx.x, wid = t >> 6, lane = t & 63;

    for (int i = t; i < 288; i += 256) l_in[i] = fcin[blockIdx.x * 288 + i];
    __syncthreads();

    const int b0i = blockIdx.x * 8 + wid * 2;
    const uint32_t* in0 = &l_in[wid * 72];

    int pc0[9], pc1[9];
    #pragma unroll
    for (int q = 0; q < 9; q++) { pc0[q] = 0; pc1[q] = 0; }

    for (int w = 0; w < 36; w++) {
        uint32_t i0 = in0[w], i1 = in0[36 + w];
        const uint32_t* wf = wfcb + w * 576 + lane;
        #pragma unroll
        for (int q = 0; q < 9; q++) {
            uint32_t f = wf[q * 64];
            pc0[q] += __popc(i0 ^ f);
            pc1[q] += __popc(i1 ^ f);
        }
    }

    float oa[2][10];
    #pragma unroll
    for (int b = 0; b < 2; b++)
        #pragma unroll
        for (int k = 0; k < 10; k++) oa[b][k] = 0.f;

    #pragma unroll
    for (int q = 0; q < 9; q++) {
        int j = lane + 64 * q;
        float ivv = inv3p[j], shv = sh3p[j];
        float t0 = fminf(1.f, fmaxf(-1.f, __fadd_rn(__fmul_rn((float)(1152 - 2 * pc0[q]), ivv), shv)));
        float t1 = fminf(1.f, fmaxf(-1.f, __fadd_rn(__fmul_rn((float)(1152 - 2 * pc1[q]), ivv), shv)));
        #pragma unroll
        for (int k = 0; k < 10; k++) {
            float wv = wlt[k * 576 + j];  // coalesced across lanes
            oa[0][k] = fmaf(t0, wv, oa[0][k]);
            oa[1][k] = fmaf(t1, wv, oa[1][k]);
        }
    }

    #pragma unroll
    for (int m = 1; m < 64; m <<= 1)
        #pragma unroll
        for (int b = 0; b < 2; b++)
            #pragma unroll
            for (int k = 0; k < 10; k++)
                oa[b][k] += __shfl_xor(oa[b][k], m, 64);

    if (lane == 0) {
        for (int b = 0; b < 2; b++)
            for (int k = 0; k < 10; k++)
                out[(b0i + b) * 10 + k] = oa[b][k] + blast[k];
    }
}

// ============================== launch ==============================
extern "C" void kernel_launch(void* const* d_in, const int* in_sizes, int n_in,
                              void* d_out, int out_size, void* d_ws, size_t ws_size,
                              hipStream_t stream)
{
    (void)in_sizes; (void)n_in; (void)out_size; (void)ws_size;
    const float* x     = (const float*)d_in[0];
    const float* w0    = (const float*)d_in[1];
    const float* b0    = (const float*)d_in[2];
    const float* g1    = (const float*)d_in[3];
    const float* be1   = (const float*)d_in[4];
    const float* m1    = (const float*)d_in[5];
    const float* v1    = (const float*)d_in[6];
    const float* w2    = (const float*)d_in[7];
    const float* g2    = (const float*)d_in[8];
    const float* be2   = (const float*)d_in[9];
    const float* m2    = (const float*)d_in[10];
    const float* v2    = (const float*)d_in[11];
    const float* wfc   = (const float*)d_in[12];
    const float* g3    = (const float*)d_in[13];
    const float* be3   = (const float*)d_in[14];
    const float* m3    = (const float*)d_in[15];
    const float* v3    = (const float*)d_in[16];
    const float* wlast = (const float*)d_in[17];
    const float* blast = (const float*)d_in[18];

    char* ws = (char*)d_ws;
    uint32_t* s1bits = (uint32_t*)(ws);                 // 8192*196*4 = 6,422,528 B
    uint32_t* fcin   = (uint32_t*)(ws + 6422528);       // 8192*36*4  = 1,179,648 B
    uint32_t* w2bits = (uint32_t*)(ws + 7602176);       // 288*4
    uint32_t* wfcb   = (uint32_t*)(ws + 7603328);       // 36*576*4 = 82,944 B
    float*    inv3p  = (float*)(ws + 7686272);          // 576*4
    float*    sh3p   = (float*)(ws + 7688576);          // 576*4
    float*    wlt    = (float*)(ws + 7690880);          // 10*576*4 = 23,040 B

    prep_kernel<<<107, 256, 0, stream>>>(w2, wfc, g3, be3, m3, v3, wlast,
                                         w2bits, wfcb, inv3p, sh3p, wlt);
    convA<<<7168, 256, 0, stream>>>(x, w0, b0, g1, be1, m1, v1, s1bits);
    convB<<<2048, 256, 0, stream>>>(s1bits, w2bits, g2, be2, m2, v2, fcin);
    fcC<<<1024, 256, 0, stream>>>(fcin, wfcb, inv3p, sh3p, wlt, blast, (float*)d_out);
}

// Round 4
// 287.100 us; speedup vs baseline: 1.2804x; 1.2804x over previous
//
#include <hip/hip_runtime.h>
#include <cstdint>

#define EPSF 1e-5f

typedef __attribute__((ext_vector_type(8))) short short8;
typedef __attribute__((ext_vector_type(4))) float f32x4;
typedef __attribute__((ext_vector_type(4))) unsigned int u32x4;

// RNE float -> bf16 bits (inputs always finite here)
__device__ inline uint32_t bf16rne(float x) {
    uint32_t u = __builtin_bit_cast(uint32_t, x);
    return (u + 0x7fffu + ((u >> 16) & 1u)) >> 16;
}
__device__ inline float bf16f(uint32_t b) {
    return __builtin_bit_cast(float, b << 16);
}

// ============================== prep ==============================
// w2bits: [co][tap] bit=ci.  wfcb: POS-MAJOR [pos][j] bit=c.  wlt: [k][j] pad576.
__global__ __launch_bounds__(256) void prep_kernel(
    const float* __restrict__ w2, const float* __restrict__ wfc,
    const float* __restrict__ g3, const float* __restrict__ be3,
    const float* __restrict__ m3, const float* __restrict__ v3,
    const float* __restrict__ wlast,
    uint32_t* __restrict__ w2bits, uint32_t* __restrict__ wfcb,
    float* __restrict__ inv3p, float* __restrict__ sh3p, float* __restrict__ wlt)
{
    int id = blockIdx.x * 256 + threadIdx.x;
    if (id < 288) {
        int co = id / 9, r = id % 9;
        uint32_t b = 0;
        for (int ci = 0; ci < 32; ci++)
            b |= (uint32_t)(w2[(co * 32 + ci) * 9 + r] < 0.f) << ci;
        w2bits[id] = b;
        return;
    }
    id -= 288;
    if (id < 36 * 576) {
        int pos = id / 576, j = id % 576;
        uint32_t b = 0;
        if (j < 516) {
            const float* row = wfc + j * 1152 + pos;
            for (int c = 0; c < 32; c++)
                b |= (uint32_t)(row[c * 36] < 0.f) << c;
        }
        wfcb[id] = b;
        return;
    }
    id -= 36 * 576;
    if (id < 576) {
        float iv = 0.f, sh = 0.f;
        if (id < 516) {
            iv = g3[id] / sqrtf(__fadd_rn(v3[id], EPSF));
            sh = __fsub_rn(be3[id], __fmul_rn(m3[id], iv));
        }
        inv3p[id] = iv; sh3p[id] = sh;
        return;
    }
    id -= 576;
    if (id < 5760) {
        int k = id / 576, j = id % 576;
        wlt[id] = (j < 516) ? wlast[k * 516 + j] : 0.f;
    }
}

// ================== conv1 fp64 sign recheck (rare) ==================
__device__ __noinline__ bool recheck_sign(const float* __restrict__ xim,
                                          const float* __restrict__ w0,
                                          int py, int px, int co,
                                          float b0c, float ivc, float shc)
{
    double ad = 0.0;
    for (int ci = 0; ci < 8; ci++)
        for (int ky = 0; ky < 3; ky++)
            for (int kx = 0; kx < 3; kx++)
                ad = fma((double)xim[ci * 256 + (py + ky) * 16 + px + kx],
                         (double)w0[co * 72 + ci * 9 + ky * 3 + kx], ad);
    double yd = (ad + (double)b0c) * (double)ivc + (double)shc;
    return yd < 0.0;
}

// ============================== convA ==============================
// conv1 via split-bf16 MFMA implicit GEMM. x = hi+lo bf16, w = hi+lo bf16;
// acc += Ah*Bh + Ah*Bl + Al*Bh (dropped lo*lo <= ~3e-5, inside the 3e-4
// fp64-recheck trigger). M=16 positions, N=16 co (x2 tiles), K=32 = 4 taps
// x 8 ci, 3 K-steps (taps 9..11 padded with w=0).
// Block = 256 thr = 4 waves = 2 images; 2 waves per image (tiles 0-6 / 7-12).
// LDS per image: 288 slots x 48B ([hi8 bf16][lo8 bf16][16B pad]) — 12-bank
// slot stride keeps ds_read_b128 conflict-free.
__global__ __launch_bounds__(256, 4) void convA(
    const float* __restrict__ x, const float* __restrict__ w0,
    const float* __restrict__ b0, const float* __restrict__ g1,
    const float* __restrict__ be1, const float* __restrict__ m1,
    const float* __restrict__ v1, uint32_t* __restrict__ s1bits)
{
    __shared__ __align__(16) char simg[2][288 * 48];

    const int t = threadIdx.x;
    const int wv = t >> 6, lane = t & 63;
    const int ilocal = wv >> 1;           // image within block
    const int w01 = wv & 1;               // wave within image
    const int img = blockIdx.x * 2 + ilocal;
    const float* xim = x + img * 2048;
    char* myimg = simg[ilocal];

    const int g = lane >> 4;              // quad = tap-in-step / C-row group
    const int n = lane & 15;              // co-within-tile / A-row pos low bits

    // ---- stage: each wave loads half the image's positions, converts, packs
    {
        const int p0 = w01 * 128 + lane * 2;
        uint32_t hw0[4], lw0[4], hw1[4], lw1[4];
        #pragma unroll
        for (int ci2 = 0; ci2 < 4; ci2++) {
            int ciA = 2 * ci2, ciB = 2 * ci2 + 1;
            float2 a = *(const float2*)(xim + ciA * 256 + p0);
            float2 b = *(const float2*)(xim + ciB * 256 + p0);
            uint32_t haA = bf16rne(a.x), haB = bf16rne(b.x);
            uint32_t hbA = bf16rne(a.y), hbB = bf16rne(b.y);
            uint32_t laA = bf16rne(a.x - bf16f(haA)), laB = bf16rne(b.x - bf16f(haB));
            uint32_t lbA = bf16rne(a.y - bf16f(hbA)), lbB = bf16rne(b.y - bf16f(hbB));
            hw0[ci2] = haA | (haB << 16);  lw0[ci2] = laA | (laB << 16);
            hw1[ci2] = hbA | (hbB << 16);  lw1[ci2] = lbA | (lbB << 16);
        }
        *(u32x4*)(myimg + p0 * 48)            = (u32x4){hw0[0], hw0[1], hw0[2], hw0[3]};
        *(u32x4*)(myimg + p0 * 48 + 16)       = (u32x4){lw0[0], lw0[1], lw0[2], lw0[3]};
        *(u32x4*)(myimg + (p0 + 1) * 48)      = (u32x4){hw1[0], hw1[1], hw1[2], hw1[3]};
        *(u32x4*)(myimg + (p0 + 1) * 48 + 16) = (u32x4){lw1[0], lw1[1], lw1[2], lw1[3]};
    }

    // ---- B fragments: B[k = quad*8 + ci][n = co&15], per (ntile, step), hi/lo
    short8 Bh[2][3], Bl[2][3];
    #pragma unroll
    for (int nt = 0; nt < 2; nt++)
        #pragma unroll
        for (int s = 0; s < 3; s++) {
            int tap = 4 * s + g;
            uint32_t hw[4] = {0, 0, 0, 0}, lw[4] = {0, 0, 0, 0};
            if (tap < 9) {
                int co = nt * 16 + n;
                #pragma unroll
                for (int j2 = 0; j2 < 4; j2++) {
                    float wa = w0[co * 72 + (2 * j2) * 9 + tap];
                    float wb = w0[co * 72 + (2 * j2 + 1) * 9 + tap];
                    uint32_t ha = bf16rne(wa), hb = bf16rne(wb);
                    uint32_t la = bf16rne(wa - bf16f(ha)), lb = bf16rne(wb - bf16f(hb));
                    hw[j2] = ha | (hb << 16);
                    lw[j2] = la | (lb << 16);
                }
            }
            union { uint32_t u[4]; short8 s8; } ch, cl;
            ch.u[0] = hw[0]; ch.u[1] = hw[1]; ch.u[2] = hw[2]; ch.u[3] = hw[3];
            cl.u[0] = lw[0]; cl.u[1] = lw[1]; cl.u[2] = lw[2]; cl.u[3] = lw[3];
            Bh[nt][s] = ch.s8; Bl[nt][s] = cl.s8;
        }

    // per-lane A LDS offsets per K-step (tap window), pad-taps -> 0 (w=0)
    int koff[3];
    #pragma unroll
    for (int s = 0; s < 3; s++) {
        int tap = 4 * s + g;
        koff[s] = (tap < 9) ? ((tap / 3) * 16 + (tap % 3)) * 48 : 0;
    }

    // per-lane BN/bias constants for co = n and co = n+16
    const int co0 = n, co1 = 16 + n;
    float b00 = b0[co0], b01 = b0[co1];
    float iv0 = g1[co0] / sqrtf(__fadd_rn(v1[co0], EPSF));
    float iv1 = g1[co1] / sqrtf(__fadd_rn(v1[co1], EPSF));
    float sh0 = __fsub_rn(be1[co0], __fmul_rn(m1[co0], iv0));
    float sh1 = __fsub_rn(be1[co1], __fmul_rn(m1[co1], iv1));

    __syncthreads();

    const int tstart = w01 ? 7 : 0, tend = w01 ? 13 : 7;
    uint32_t* outb = s1bits + img * 196;

    for (int tile = tstart; tile < tend; ++tile) {
        int posA = tile * 16 + n;         // this lane's A row (may be >=196: discarded)
        int pyA = posA / 14, pxA = posA - pyA * 14;
        const char* abase = myimg + (pyA * 16 + pxA) * 48;

        f32x4 acc0 = {0.f, 0.f, 0.f, 0.f}, acc1 = {0.f, 0.f, 0.f, 0.f};
        #pragma unroll
        for (int s = 0; s < 3; s++) {
            short8 Ah = *(const short8*)(abase + koff[s]);
            short8 Al = *(const short8*)(abase + koff[s] + 16);
            acc0 = __builtin_amdgcn_mfma_f32_16x16x32_bf16(Al, Bh[0][s], acc0, 0, 0, 0);
            acc0 = __builtin_amdgcn_mfma_f32_16x16x32_bf16(Ah, Bl[0][s], acc0, 0, 0, 0);
            acc0 = __builtin_amdgcn_mfma_f32_16x16x32_bf16(Ah, Bh[0][s], acc0, 0, 0, 0);
            acc1 = __builtin_amdgcn_mfma_f32_16x16x32_bf16(Al, Bh[1][s], acc1, 0, 0, 0);
            acc1 = __builtin_amdgcn_mfma_f32_16x16x32_bf16(Ah, Bl[1][s], acc1, 0, 0, 0);
            acc1 = __builtin_amdgcn_mfma_f32_16x16x32_bf16(Ah, Bh[1][s], acc1, 0, 0, 0);
        }

        // epilogue: C/D row = 4*g + r, col = n (co / co+16)
        #pragma unroll
        for (int r = 0; r < 4; r++) {
            int row = 4 * g + r;
            int pos = tile * 16 + row;    // per-lane (g varies)
            float yv0 = __fadd_rn(__fmul_rn(__fadd_rn(acc0[r], b00), iv0), sh0);
            float yv1 = __fadd_rn(__fmul_rn(__fadd_rn(acc1[r], b01), iv1), sh1);
            bool bit0, bit1;
            if (__builtin_expect(pos < 196 && fabsf(yv0) < 3e-4f, 0)) {
                int py = pos / 14, px = pos - py * 14;
                bit0 = recheck_sign(xim, w0, py, px, co0, b00, iv0, sh0);
            } else bit0 = (yv0 < 0.f);
            if (__builtin_expect(pos < 196 && fabsf(yv1) < 3e-4f, 0)) {
                int py = pos / 14, px = pos - py * 14;
                bit1 = recheck_sign(xim, w0, py, px, co1, b01, iv1, sh1);
            } else bit1 = (yv1 < 0.f);
            unsigned long long m0 = __ballot(bit0);
            unsigned long long m1 = __ballot(bit1);
            uint32_t word = (uint32_t)((m0 >> (16 * g)) & 0xffffull)
                          | ((uint32_t)((m1 >> (16 * g)) & 0xffffull) << 16);
            if (n == 0 && pos < 196) outb[pos] = word;
        }
    }
}

// ============================== convB ==============================
// binary conv2 + BN2 + hardtanh + maxpool + sign. One image per wave.
// Output POS-MAJOR: fcin[img*36 + pos], bit c.
__global__ __launch_bounds__(256) void convB(
    const uint32_t* __restrict__ s1bits, const uint32_t* __restrict__ w2bits,
    const float* __restrict__ g2, const float* __restrict__ be2,
    const float* __restrict__ m2, const float* __restrict__ v2,
    uint32_t* __restrict__ fcin)
{
    __shared__ uint32_t s1l[4][196];
    const int t = threadIdx.x, wid = t >> 6, lane = t & 63;
    const int img = blockIdx.x * 4 + wid;

    for (int i = lane; i < 196; i += 64) s1l[wid][i] = s1bits[img * 196 + i];

    const int c = lane & 31, h = lane >> 5;
    uint32_t wr[9];
    #pragma unroll
    for (int k = 0; k < 9; k++) wr[k] = w2bits[c * 9 + k];
    float ivv = g2[c] / sqrtf(__fadd_rn(v2[c], EPSF));
    float shv = __fsub_rn(be2[c], __fmul_rn(m2[c], ivv));
    __syncthreads();

    const uint32_t* s1w = s1l[wid];
    uint32_t* outp = fcin + img * 36;

    for (int yy = 0; yy < 3; yy++) {
        const int y2 = yy + 3 * h;
        const int rbase = 2 * y2 * 14;
        uint32_t win[4][4];
        #pragma unroll
        for (int rr = 0; rr < 4; rr++) {
            uint2 a = *(const uint2*)&s1w[rbase + rr * 14];
            uint2 b = *(const uint2*)&s1w[rbase + rr * 14 + 2];
            win[rr][0] = a.x; win[rr][1] = a.y; win[rr][2] = b.x; win[rr][3] = b.y;
        }
        for (int x2 = 0; x2 < 6; x2++) {
            if (x2 > 0) {
                #pragma unroll
                for (int rr = 0; rr < 4; rr++) {
                    win[rr][0] = win[rr][2]; win[rr][1] = win[rr][3];
                    uint2 b = *(const uint2*)&s1w[rbase + rr * 14 + 2 * x2 + 2];
                    win[rr][2] = b.x; win[rr][3] = b.y;
                }
            }
            int mx = -10000;
            #pragma unroll
            for (int dy = 0; dy < 2; dy++)
                #pragma unroll
                for (int dx = 0; dx < 2; dx++) {
                    int p = 0;
                    #pragma unroll
                    for (int ky = 0; ky < 3; ky++)
                        #pragma unroll
                        for (int kx = 0; kx < 3; kx++)
                            p += __popc(win[dy + ky][dx + kx] ^ wr[ky * 3 + kx]);
                    mx = max(mx, 288 - 2 * p);
                }
            float yv = __fadd_rn(__fmul_rn((float)mx, ivv), shv);
            unsigned long long mb = __ballot(yv < 0.f);
            int pos = y2 * 6 + x2;
            if (lane == 0)  outp[pos] = (uint32_t)mb;
            if (lane == 32) outp[pos] = (uint32_t)(mb >> 32);
        }
    }
}

// ============================== fcC ==============================
// binary FC + BN3 + hardtanh + final 516x10 linear. wave = 2 batches.
__global__ __launch_bounds__(256) void fcC(
    const uint32_t* __restrict__ fcin, const uint32_t* __restrict__ wfcb,
    const float* __restrict__ inv3p, const float* __restrict__ sh3p,
    const float* __restrict__ wlt, const float* __restrict__ blast,
    float* __restrict__ out)
{
    __shared__ uint32_t l_in[288];
    const int t = threadIdx.x, wid = t >> 6, lane = t & 63;

    for (int i = t; i < 288; i += 256) l_in[i] = fcin[blockIdx.x * 288 + i];
    __syncthreads();

    const int b0i = blockIdx.x * 8 + wid * 2;
    const uint32_t* in0 = &l_in[wid * 72];

    int pc0[9], pc1[9];
    #pragma unroll
    for (int q = 0; q < 9; q++) { pc0[q] = 0; pc1[q] = 0; }

    for (int w = 0; w < 36; w++) {
        uint32_t i0 = in0[w], i1 = in0[36 + w];
        const uint32_t* wf = wfcb + w * 576 + lane;
        #pragma unroll
        for (int q = 0; q < 9; q++) {
            uint32_t f = wf[q * 64];
            pc0[q] += __popc(i0 ^ f);
            pc1[q] += __popc(i1 ^ f);
        }
    }

    float oa[2][10];
    #pragma unroll
    for (int b = 0; b < 2; b++)
        #pragma unroll
        for (int k = 0; k < 10; k++) oa[b][k] = 0.f;

    #pragma unroll
    for (int q = 0; q < 9; q++) {
        int j = lane + 64 * q;
        float ivv = inv3p[j], shv = sh3p[j];
        float t0 = fminf(1.f, fmaxf(-1.f, __fadd_rn(__fmul_rn((float)(1152 - 2 * pc0[q]), ivv), shv)));
        float t1 = fminf(1.f, fmaxf(-1.f, __fadd_rn(__fmul_rn((float)(1152 - 2 * pc1[q]), ivv), shv)));
        #pragma unroll
        for (int k = 0; k < 10; k++) {
            float wv = wlt[k * 576 + j];
            oa[0][k] = fmaf(t0, wv, oa[0][k]);
            oa[1][k] = fmaf(t1, wv, oa[1][k]);
        }
    }

    #pragma unroll
    for (int m = 1; m < 64; m <<= 1)
        #pragma unroll
        for (int b = 0; b < 2; b++)
            #pragma unroll
            for (int k = 0; k < 10; k++)
                oa[b][k] += __shfl_xor(oa[b][k], m, 64);

    if (lane == 0) {
        for (int b = 0; b < 2; b++)
            for (int k = 0; k < 10; k++)
                out[(b0i + b) * 10 + k] = oa[b][k] + blast[k];
    }
}

// ============================== launch ==============================
extern "C" void kernel_launch(void* const* d_in, const int* in_sizes, int n_in,
                              void* d_out, int out_size, void* d_ws, size_t ws_size,
                              hipStream_t stream)
{
    (void)in_sizes; (void)n_in; (void)out_size; (void)ws_size;
    const float* x     = (const float*)d_in[0];
    const float* w0    = (const float*)d_in[1];
    const float* b0    = (const float*)d_in[2];
    const float* g1    = (const float*)d_in[3];
    const float* be1   = (const float*)d_in[4];
    const float* m1    = (const float*)d_in[5];
    const float* v1    = (const float*)d_in[6];
    const float* w2    = (const float*)d_in[7];
    const float* g2    = (const float*)d_in[8];
    const float* be2   = (const float*)d_in[9];
    const float* m2    = (const float*)d_in[10];
    const float* v2    = (const float*)d_in[11];
    const float* wfc   = (const float*)d_in[12];
    const float* g3    = (const float*)d_in[13];
    const float* be3   = (const float*)d_in[14];
    const float* m3    = (const float*)d_in[15];
    const float* v3    = (const float*)d_in[16];
    const float* wlast = (const float*)d_in[17];
    const float* blast = (const float*)d_in[18];

    char* ws = (char*)d_ws;
    uint32_t* s1bits = (uint32_t*)(ws);                 // 8192*196*4 = 6,422,528 B
    uint32_t* fcin   = (uint32_t*)(ws + 6422528);       // 8192*36*4  = 1,179,648 B
    uint32_t* w2bits = (uint32_t*)(ws + 7602176);       // 288*4
    uint32_t* wfcb   = (uint32_t*)(ws + 7603328);       // 36*576*4 = 82,944 B
    float*    inv3p  = (float*)(ws + 7686272);          // 576*4
    float*    sh3p   = (float*)(ws + 7688576);          // 576*4
    float*    wlt    = (float*)(ws + 7690880);          // 10*576*4 = 23,040 B

    prep_kernel<<<107, 256, 0, stream>>>(w2, wfc, g3, be3, m3, v3, wlast,
                                         w2bits, wfcb, inv3p, sh3p, wlt);
    convA<<<4096, 256, 0, stream>>>(x, w0, b0, g1, be1, m1, v1, s1bits);
    convB<<<2048, 256, 0, stream>>>(s1bits, w2bits, g2, be2, m2, v2, fcin);
    fcC<<<1024, 256, 0, stream>>>(fcin, wfcb, inv3p, sh3p, wlt, blast, (float*)d_out);
}

// Round 5
// 225.039 us; speedup vs baseline: 1.6335x; 1.2758x over previous
//
#include <hip/hip_runtime.h>
#include <cstdint>

#define EPSF 1e-5f

typedef __attribute__((ext_vector_type(8))) short short8;
typedef __attribute__((ext_vector_type(4))) float f32x4;
typedef __attribute__((ext_vector_type(4))) unsigned int u32x4;

// RNE float -> bf16 bits (inputs always finite here)
__device__ inline uint32_t bf16rne(float x) {
    uint32_t u = __builtin_bit_cast(uint32_t, x);
    return (u + 0x7fffu + ((u >> 16) & 1u)) >> 16;
}
__device__ inline float bf16f(uint32_t b) {
    return __builtin_bit_cast(float, b << 16);
}

// ============================== prep ==============================
// id ranges:
//  [0,288)          w2bits [co][tap] bit=ci
//  [288,21024)      wfcb POS-MAJOR [pos][j] bit=c, id ordered j-major for
//                   coalesced READS of wfc (old pos-major order fetched ~2048
//                   cachelines/wave; writes are only 83KB total)
//  [21024,21600)    BN3 (iv, sh) padded to 576
//  [21600,27360)    wlt [k][j] pad576
//  [27360,28128)    convA B-fragments in final per-lane layout:
//                   q = L*12 + nt*6 + s*2 + h  ->  u32x4 at bfrag + q*16B
//  [28128,28160)    BN1 folded (iv, off=b0*iv+sh) as float2[32]
__global__ __launch_bounds__(256) void prep_kernel(
    const float* __restrict__ w2, const float* __restrict__ wfc,
    const float* __restrict__ g3, const float* __restrict__ be3,
    const float* __restrict__ m3, const float* __restrict__ v3,
    const float* __restrict__ wlast,
    const float* __restrict__ w0, const float* __restrict__ b0,
    const float* __restrict__ g1, const float* __restrict__ be1,
    const float* __restrict__ m1, const float* __restrict__ v1,
    uint32_t* __restrict__ w2bits, uint32_t* __restrict__ wfcb,
    float* __restrict__ inv3p, float* __restrict__ sh3p, float* __restrict__ wlt,
    uint32_t* __restrict__ bfrag, float2* __restrict__ bn1c)
{
    int id = blockIdx.x * 256 + threadIdx.x;
    if (id < 288) {
        int co = id / 9, r = id % 9;
        uint32_t b = 0;
        for (int ci = 0; ci < 32; ci++)
            b |= (uint32_t)(w2[(co * 32 + ci) * 9 + r] < 0.f) << ci;
        w2bits[id] = b;
        return;
    }
    id -= 288;
    if (id < 36 * 576) {                  // j-major iteration, pos-major storage
        int j = id / 36, pos = id % 36;
        uint32_t b = 0;
        if (j < 516) {
            const float* row = wfc + j * 1152 + pos;
            for (int c = 0; c < 32; c++)
                b |= (uint32_t)(row[c * 36] < 0.f) << c;
        }
        wfcb[pos * 576 + j] = b;
        return;
    }
    id -= 36 * 576;
    if (id < 576) {
        float iv = 0.f, sh = 0.f;
        if (id < 516) {
            iv = g3[id] / sqrtf(__fadd_rn(v3[id], EPSF));
            sh = __fsub_rn(be3[id], __fmul_rn(m3[id], iv));
        }
        inv3p[id] = iv; sh3p[id] = sh;
        return;
    }
    id -= 576;
    if (id < 5760) {
        int k = id / 576, j = id % 576;
        wlt[id] = (j < 516) ? wlast[k * 516 + j] : 0.f;
        return;
    }
    id -= 5760;
    if (id < 768) {                       // B fragments
        int L = id / 12, r = id % 12;
        int nt = r / 6, s = (r % 6) / 2, h = r & 1;
        int g = L >> 4, n = L & 15;
        int tap = 4 * s + g;
        uint32_t d[4] = {0, 0, 0, 0};
        if (tap < 9) {
            int co = nt * 16 + n;
            for (int j2 = 0; j2 < 4; j2++) {
                float wa = w0[co * 72 + (2 * j2) * 9 + tap];
                float wb = w0[co * 72 + (2 * j2 + 1) * 9 + tap];
                uint32_t ha = bf16rne(wa), hb = bf16rne(wb);
                uint32_t va, vb;
                if (h == 0) { va = ha; vb = hb; }
                else { va = bf16rne(wa - bf16f(ha)); vb = bf16rne(wb - bf16f(hb)); }
                d[j2] = va | (vb << 16);
            }
        }
        *(u32x4*)(bfrag + id * 4) = (u32x4){d[0], d[1], d[2], d[3]};
        return;
    }
    id -= 768;
    if (id < 32) {                        // BN1 folded constants
        float iv = g1[id] / sqrtf(__fadd_rn(v1[id], EPSF));
        float sh = __fsub_rn(be1[id], __fmul_rn(m1[id], iv));
        float off = __fadd_rn(__fmul_rn(b0[id], iv), sh);
        bn1c[id] = make_float2(iv, off);
    }
}

// ================== conv1 fp64 sign recheck (rare) ==================
__device__ __noinline__ bool recheck_sign(const float* __restrict__ xim,
                                          const float* __restrict__ w0,
                                          int py, int px, int co,
                                          float ivc, float offc)
{
    double ad = 0.0;
    for (int ci = 0; ci < 8; ci++)
        for (int ky = 0; ky < 3; ky++)
            for (int kx = 0; kx < 3; kx++)
                ad = fma((double)xim[ci * 256 + (py + ky) * 16 + px + kx],
                         (double)w0[co * 72 + ci * 9 + ky * 3 + kx], ad);
    return (ad * (double)ivc + (double)offc) < 0.0;
}

// ============================== convA ==============================
// conv1 via split-bf16 MFMA implicit GEMM (validated layout, R4).
// Block = 128 thr = 2 waves = 2 images; one wave per image, 13 M-tiles.
// All wave-invariant setup (B-frags, BN) preloaded from prep's output.
// LDS per image: hi-plane 288x16B + lo-plane 288x16B = 9216 B (16B slot
// stride: 2-way bank aliasing only, b128-aligned).
__global__ __launch_bounds__(128, 4) void convA(
    const float* __restrict__ x, const float* __restrict__ w0,
    const uint32_t* __restrict__ bfrag, const float2* __restrict__ bn1c,
    uint32_t* __restrict__ s1bits)
{
    __shared__ __align__(16) char simg[2][9216];

    const int t = threadIdx.x;
    const int wv = t >> 6, lane = t & 63;
    const int img = blockIdx.x * 2 + wv;
    const float* xim = x + img * 2048;
    char* hib = simg[wv];
    char* lob = simg[wv] + 4608;

    const int g = lane >> 4;              // quad
    const int n = lane & 15;

    // ---- B fragments: 12 x 16B per lane, precomputed in prep
    short8 Bh[2][3], Bl[2][3];
    {
        const uint32_t* bb = bfrag + lane * 48;
        #pragma unroll
        for (int nt = 0; nt < 2; nt++)
            #pragma unroll
            for (int s = 0; s < 3; s++) {
                Bh[nt][s] = *(const short8*)(bb + (nt * 6 + s * 2) * 4);
                Bl[nt][s] = *(const short8*)(bb + (nt * 6 + s * 2 + 1) * 4);
            }
    }
    const float2 bnA = bn1c[n], bnB = bn1c[16 + n];

    // ---- stage image: pos = lane + 64q; hi/lo bf16 planes
    #pragma unroll
    for (int q = 0; q < 4; q++) {
        int pos = lane + 64 * q;
        uint32_t hw[4], lw[4];
        #pragma unroll
        for (int j2 = 0; j2 < 4; j2++) {
            float a = xim[(2 * j2) * 256 + pos];
            float b = xim[(2 * j2 + 1) * 256 + pos];
            uint32_t ha = bf16rne(a), hb = bf16rne(b);
            uint32_t la = bf16rne(a - bf16f(ha)), lb = bf16rne(b - bf16f(hb));
            hw[j2] = ha | (hb << 16);
            lw[j2] = la | (lb << 16);
        }
        *(u32x4*)(hib + pos * 16) = (u32x4){hw[0], hw[1], hw[2], hw[3]};
        *(u32x4*)(lob + pos * 16) = (u32x4){lw[0], lw[1], lw[2], lw[3]};
    }
    if (lane < 32) {                      // zero guard slots 256..287
        *(u32x4*)(hib + (256 + lane) * 16) = (u32x4){0, 0, 0, 0};
        *(u32x4*)(lob + (256 + lane) * 16) = (u32x4){0, 0, 0, 0};
    }

    // per-lane A LDS byte offsets per K-step (tap window); pad-taps -> 0 (B=0)
    int koff[3];
    #pragma unroll
    for (int s = 0; s < 3; s++) {
        int tap = 4 * s + g;
        koff[s] = (tap < 9) ? ((tap / 3) * 16 + (tap % 3)) * 16 : 0;
    }

    __syncthreads();

    uint32_t* outb = s1bits + img * 196;

    for (int tile = 0; tile < 13; ++tile) {
        int posA = tile * 16 + n;
        int pyA = posA / 14, pxA = posA - pyA * 14;
        int sl = (pyA * 16 + pxA) * 16;

        f32x4 acc0 = {0.f, 0.f, 0.f, 0.f}, acc1 = {0.f, 0.f, 0.f, 0.f};
        #pragma unroll
        for (int s = 0; s < 3; s++) {
            short8 Ah = *(const short8*)(hib + sl + koff[s]);
            short8 Al = *(const short8*)(lob + sl + koff[s]);
            acc0 = __builtin_amdgcn_mfma_f32_16x16x32_bf16(Al, Bh[0][s], acc0, 0, 0, 0);
            acc0 = __builtin_amdgcn_mfma_f32_16x16x32_bf16(Ah, Bl[0][s], acc0, 0, 0, 0);
            acc0 = __builtin_amdgcn_mfma_f32_16x16x32_bf16(Ah, Bh[0][s], acc0, 0, 0, 0);
            acc1 = __builtin_amdgcn_mfma_f32_16x16x32_bf16(Al, Bh[1][s], acc1, 0, 0, 0);
            acc1 = __builtin_amdgcn_mfma_f32_16x16x32_bf16(Ah, Bl[1][s], acc1, 0, 0, 0);
            acc1 = __builtin_amdgcn_mfma_f32_16x16x32_bf16(Ah, Bh[1][s], acc1, 0, 0, 0);
        }

        // epilogue: C/D row = 4*g + r (pos), col = n (co / co+16)
        #pragma unroll
        for (int r = 0; r < 4; r++) {
            int pos = tile * 16 + 4 * g + r;
            float yv0 = fmaf(acc0[r], bnA.x, bnA.y);
            float yv1 = fmaf(acc1[r], bnB.x, bnB.y);
            bool bit0, bit1;
            if (__builtin_expect(pos < 196 && fabsf(yv0) < 3e-4f, 0)) {
                int py = pos / 14, px = pos - py * 14;
                bit0 = recheck_sign(xim, w0, py, px, n, bnA.x, bnA.y);
            } else bit0 = (yv0 < 0.f);
            if (__builtin_expect(pos < 196 && fabsf(yv1) < 3e-4f, 0)) {
                int py = pos / 14, px = pos - py * 14;
                bit1 = recheck_sign(xim, w0, py, px, 16 + n, bnB.x, bnB.y);
            } else bit1 = (yv1 < 0.f);
            unsigned long long m0 = __ballot(bit0);
            unsigned long long m1 = __ballot(bit1);
            uint32_t word = (uint32_t)((m0 >> (16 * g)) & 0xffffull)
                          | ((uint32_t)((m1 >> (16 * g)) & 0xffffull) << 16);
            if (n == 0 && pos < 196) outb[pos] = word;
        }
    }
}

// ============================== convB ==============================
// binary conv2 + BN2 + hardtanh + maxpool + sign. One image per wave.
// Output POS-MAJOR: fcin[img*36 + pos], bit c.
__global__ __launch_bounds__(256) void convB(
    const uint32_t* __restrict__ s1bits, const uint32_t* __restrict__ w2bits,
    const float* __restrict__ g2, const float* __restrict__ be2,
    const float* __restrict__ m2, const float* __restrict__ v2,
    uint32_t* __restrict__ fcin)
{
    __shared__ uint32_t s1l[4][196];
    const int t = threadIdx.x, wid = t >> 6, lane = t & 63;
    const int img = blockIdx.x * 4 + wid;

    for (int i = lane; i < 196; i += 64) s1l[wid][i] = s1bits[img * 196 + i];

    const int c = lane & 31, h = lane >> 5;
    uint32_t wr[9];
    #pragma unroll
    for (int k = 0; k < 9; k++) wr[k] = w2bits[c * 9 + k];
    float ivv = g2[c] / sqrtf(__fadd_rn(v2[c], EPSF));
    float shv = __fsub_rn(be2[c], __fmul_rn(m2[c], ivv));
    __syncthreads();

    const uint32_t* s1w = s1l[wid];
    uint32_t* outp = fcin + img * 36;

    for (int yy = 0; yy < 3; yy++) {
        const int y2 = yy + 3 * h;
        const int rbase = 2 * y2 * 14;
        uint32_t win[4][4];
        #pragma unroll
        for (int rr = 0; rr < 4; rr++) {
            uint2 a = *(const uint2*)&s1w[rbase + rr * 14];
            uint2 b = *(const uint2*)&s1w[rbase + rr * 14 + 2];
            win[rr][0] = a.x; win[rr][1] = a.y; win[rr][2] = b.x; win[rr][3] = b.y;
        }
        for (int x2 = 0; x2 < 6; x2++) {
            if (x2 > 0) {
                #pragma unroll
                for (int rr = 0; rr < 4; rr++) {
                    win[rr][0] = win[rr][2]; win[rr][1] = win[rr][3];
                    uint2 b = *(const uint2*)&s1w[rbase + rr * 14 + 2 * x2 + 2];
                    win[rr][2] = b.x; win[rr][3] = b.y;
                }
            }
            int mx = -10000;
            #pragma unroll
            for (int dy = 0; dy < 2; dy++)
                #pragma unroll
                for (int dx = 0; dx < 2; dx++) {
                    int p = 0;
                    #pragma unroll
                    for (int ky = 0; ky < 3; ky++)
                        #pragma unroll
                        for (int kx = 0; kx < 3; kx++)
                            p += __popc(win[dy + ky][dx + kx] ^ wr[ky * 3 + kx]);
                    mx = max(mx, 288 - 2 * p);
                }
            float yv = __fadd_rn(__fmul_rn((float)mx, ivv), shv);
            unsigned long long mb = __ballot(yv < 0.f);
            int pos = y2 * 6 + x2;
            if (lane == 0)  outp[pos] = (uint32_t)mb;
            if (lane == 32) outp[pos] = (uint32_t)(mb >> 32);
        }
    }
}

// ============================== fcC ==============================
// binary FC + BN3 + hardtanh + final 516x10 linear. wave = 2 batches.
__global__ __launch_bounds__(256) void fcC(
    const uint32_t* __restrict__ fcin, const uint32_t* __restrict__ wfcb,
    const float* __restrict__ inv3p, const float* __restrict__ sh3p,
    const float* __restrict__ wlt, const float* __restrict__ blast,
    float* __restrict__ out)
{
    __shared__ uint32_t l_in[288];
    const int t = threadIdx.x, wid = t >> 6, lane = t & 63;

    for (int i = t; i < 288; i += 256) l_in[i] = fcin[blockIdx.x * 288 + i];
    __syncthreads();

    const int b0i = blockIdx.x * 8 + wid * 2;
    const uint32_t* in0 = &l_in[wid * 72];

    int pc0[9], pc1[9];
    #pragma unroll
    for (int q = 0; q < 9; q++) { pc0[q] = 0; pc1[q] = 0; }

    for (int w = 0; w < 36; w++) {
        uint32_t i0 = in0[w], i1 = in0[36 + w];
        const uint32_t* wf = wfcb + w * 576 + lane;
        #pragma unroll
        for (int q = 0; q < 9; q++) {
            uint32_t f = wf[q * 64];
            pc0[q] += __popc(i0 ^ f);
            pc1[q] += __popc(i1 ^ f);
        }
    }

    float oa[2][10];
    #pragma unroll
    for (int b = 0; b < 2; b++)
        #pragma unroll
        for (int k = 0; k < 10; k++) oa[b][k] = 0.f;

    #pragma unroll
    for (int q = 0; q < 9; q++) {
        int j = lane + 64 * q;
        float ivv = inv3p[j], shv = sh3p[j];
        float t0 = fminf(1.f, fmaxf(-1.f, __fadd_rn(__fmul_rn((float)(1152 - 2 * pc0[q]), ivv), shv)));
        float t1 = fminf(1.f, fmaxf(-1.f, __fadd_rn(__fmul_rn((float)(1152 - 2 * pc1[q]), ivv), shv)));
        #pragma unroll
        for (int k = 0; k < 10; k++) {
            float wv = wlt[k * 576 + j];
            oa[0][k] = fmaf(t0, wv, oa[0][k]);
            oa[1][k] = fmaf(t1, wv, oa[1][k]);
        }
    }

    #pragma unroll
    for (int m = 1; m < 64; m <<= 1)
        #pragma unroll
        for (int b = 0; b < 2; b++)
            #pragma unroll
            for (int k = 0; k < 10; k++)
                oa[b][k] += __shfl_xor(oa[b][k], m, 64);

    if (lane == 0) {
        for (int b = 0; b < 2; b++)
            for (int k = 0; k < 10; k++)
                out[(b0i + b) * 10 + k] = oa[b][k] + blast[k];
    }
}

// ============================== launch ==============================
extern "C" void kernel_launch(void* const* d_in, const int* in_sizes, int n_in,
                              void* d_out, int out_size, void* d_ws, size_t ws_size,
                              hipStream_t stream)
{
    (void)in_sizes; (void)n_in; (void)out_size; (void)ws_size;
    const float* x     = (const float*)d_in[0];
    const float* w0    = (const float*)d_in[1];
    const float* b0    = (const float*)d_in[2];
    const float* g1    = (const float*)d_in[3];
    const float* be1   = (const float*)d_in[4];
    const float* m1    = (const float*)d_in[5];
    const float* v1    = (const float*)d_in[6];
    const float* w2    = (const float*)d_in[7];
    const float* g2    = (const float*)d_in[8];
    const float* be2   = (const float*)d_in[9];
    const float* m2    = (const float*)d_in[10];
    const float* v2    = (const float*)d_in[11];
    const float* wfc   = (const float*)d_in[12];
    const float* g3    = (const float*)d_in[13];
    const float* be3   = (const float*)d_in[14];
    const float* m3    = (const float*)d_in[15];
    const float* v3    = (const float*)d_in[16];
    const float* wlast = (const float*)d_in[17];
    const float* blast = (const float*)d_in[18];

    char* ws = (char*)d_ws;
    uint32_t* s1bits = (uint32_t*)(ws);                 // 8192*196*4 = 6,422,528 B
    uint32_t* fcin   = (uint32_t*)(ws + 6422528);       // 8192*36*4  = 1,179,648 B
    uint32_t* w2bits = (uint32_t*)(ws + 7602176);       // 288*4
    uint32_t* wfcb   = (uint32_t*)(ws + 7603328);       // 36*576*4 = 82,944 B
    float*    inv3p  = (float*)(ws + 7686272);          // 576*4
    float*    sh3p   = (float*)(ws + 7688576);          // 576*4
    float*    wlt    = (float*)(ws + 7690880);          // 10*576*4 = 23,040 B
    uint32_t* bfrag  = (uint32_t*)(ws + 7713920);       // 768*16 = 12,288 B (16B aligned)
    float2*   bn1c   = (float2*)(ws + 7726208);         // 32*8 = 256 B

    prep_kernel<<<110, 256, 0, stream>>>(w2, wfc, g3, be3, m3, v3, wlast,
                                         w0, b0, g1, be1, m1, v1,
                                         w2bits, wfcb, inv3p, sh3p, wlt,
                                         bfrag, bn1c);
    convA<<<4096, 128, 0, stream>>>(x, w0, bfrag, bn1c, s1bits);
    convB<<<2048, 256, 0, stream>>>(s1bits, w2bits, g2, be2, m2, v2, fcin);
    fcC<<<1024, 256, 0, stream>>>(fcin, wfcb, inv3p, sh3p, wlt, blast, (float*)d_out);
}